// Round 11
// baseline (327.546 us; speedup 1.0000x reference)
//
#include <hip/hip_runtime.h>
#include <hip/hip_bf16.h>
#include <math.h>

#define NTOK 32768
#define HID  1024
#define NEXP 64
#define H4   256

typedef __attribute__((ext_vector_type(8))) short bf16x8;
typedef __attribute__((ext_vector_type(4))) float f32x4;

static __device__ __forceinline__ ushort f2bf(float x) {
    unsigned u = __float_as_uint(x);
    unsigned r = (u + 0x7FFFu + ((u >> 16) & 1u)) >> 16;   // RNE
    return (ushort)r;
}

// RNE-cascade 3-way split: x = h + m + l + O(2^-27 |x|).
static __device__ __forceinline__ void split3r(float x, ushort &h, ushort &m, ushort &l) {
    h = f2bf(x);
    const float r1 = x - __uint_as_float(((unsigned)h) << 16);
    m = f2bf(r1);
    const float r2 = r1 - __uint_as_float(((unsigned)m) << 16);
    l = f2bf(r2);
}

// ---------------------------------------------------------------------------
// Kernel 0 (prep): weights -> 16x16x32 FRAGMENT-ORDER layouts (proven r4-r8).
//   W1f[p][cg][j][piece][lane][8]  : p*16384 + cg*4096 + j*1024 + piece*512 + lane*8
//   RWf[p][cg][piece][lane][8]     : p*6144  + cg*1536 + piece*512 + lane*8
// lane = quad*16 + l15 holds W[col = tile*16 + l15][k = p*32 + quad*8 + i].
// ---------------------------------------------------------------------------
__global__ __launch_bounds__(256) void prep_kernel(
    const float* __restrict__ W1, const float* __restrict__ RW,
    ushort* __restrict__ W1f, ushort* __restrict__ RWf)
{
    if (blockIdx.x < 256) {
        const int id = blockIdx.x * 256 + threadIdx.x;
        const int c  = id >> 8;                      // 0..255 (w1 output col)
        const int k0 = (id & 255) * 4;               // 0..1020
        const float4 v = *(const float4*)(W1 + (size_t)c * HID + k0);
        const int p = k0 >> 5, quad = (k0 >> 3) & 3, kk = k0 & 7;
        const int cg = c >> 6, j = (c >> 4) & 3, l15 = c & 15;
        const int lane = quad * 16 + l15;
        const size_t base = (size_t)p * 16384 + cg * 4096 + j * 1024 + lane * 8 + kk;
        const float xs[4] = {v.x, v.y, v.z, v.w};
        ushort hv[4], lv[4];
#pragma unroll
        for (int q = 0; q < 4; q++) {
            const ushort h = f2bf(xs[q]);
            hv[q] = h;
            lv[q] = f2bf(xs[q] - __uint_as_float(((unsigned)h) << 16));
        }
        *(ushort4*)(W1f + base)       = make_ushort4(hv[0], hv[1], hv[2], hv[3]);
        *(ushort4*)(W1f + base + 512) = make_ushort4(lv[0], lv[1], lv[2], lv[3]);
    } else {
        const int e  = blockIdx.x - 256;             // expert, 0..63
        const int k0 = threadIdx.x * 4;              // 0..1020
        const float4 v = *(const float4*)(RW + (size_t)e * HID + k0);
        const int p = k0 >> 5, quad = (k0 >> 3) & 3, kk = k0 & 7;
        const int cg = e >> 4, l15 = e & 15;
        const int lane = quad * 16 + l15;
        const size_t base = (size_t)p * 6144 + cg * 1536 + lane * 8 + kk;
        const float xs[4] = {v.x, v.y, v.z, v.w};
        ushort h[4], m[4], l[4];
#pragma unroll
        for (int q = 0; q < 4; q++) split3r(xs[q], h[q], m[q], l[q]);
        *(ushort4*)(RWf + base)        = make_ushort4(h[0], h[1], h[2], h[3]);
        *(ushort4*)(RWf + base + 512)  = make_ushort4(m[0], m[1], m[2], m[3]);
        *(ushort4*)(RWf + base + 1024) = make_ushort4(l[0], l[1], l[2], l[3]);
    }
}

// ---------------------------------------------------------------------------
// Kernel 1 (v14): ZERO-LDS, ZERO-BARRIER main loop (16x16x32).
// (Round-10 resubmission: container failed twice = infra flake, same as
// round 3; source re-audited — no hang/fault path found.)
// Ledger: MfmaUtil pinned 32-34% across ALL barrier/staging schedules.
// v14 deletes the shared structure: the 8KB X panel is wanted at
// IDENTICAL addresses by all 4 waves -> L1 shares it for free. A-frags
// loaded per-lane straight from global X, split3r in-reg, 72 MFMA/panel.
// No staging, no ds ops, no s_barrier: waves drift, each SIMD's 2 waves
// cover each other's stalls. A-f32 and RW reg-dbuf; W1 same-iter first.
// ---------------------------------------------------------------------------
template<int PH>
__device__ __forceinline__ void kstep(
    int p, int cg, int lane, int quad, int l15,
    const float* __restrict__ xrow0,
    const ushort* __restrict__ RWf, const ushort* __restrict__ W1f,
    bf16x8 (&rwh)[2], bf16x8 (&rwm)[2], bf16x8 (&rwl)[2],
    float4 (&xa)[2][4][2],
    f32x4 (&accL)[4], f32x4 (&accP)[4][4])
{
    // 1. W1(p) — needed this iter, issued first (oldest in vmcnt FIFO)
    const ushort* __restrict__ w1p = W1f + (size_t)p * 16384 + cg * 4096 + lane * 8;
    bf16x8 bwh[4], bwl[4];
#pragma unroll
    for (int j = 0; j < 4; ++j) {
        bwh[j] = *(const bf16x8*)(w1p + j * 1024);
        bwl[j] = *(const bf16x8*)(w1p + j * 1024 + 512);
    }
    // 2. RW(p+1) -> next register set
    {
        const ushort* __restrict__ rwp =
            RWf + (size_t)((p + 1) & 31) * 6144 + cg * 1536 + lane * 8;
        rwh[PH ^ 1] = *(const bf16x8*)(rwp);
        rwm[PH ^ 1] = *(const bf16x8*)(rwp + 512);
        rwl[PH ^ 1] = *(const bf16x8*)(rwp + 1024);
    }
    // 3. A-f32(p+1) -> next regs: lane reads X[f*16+l15][(p+1)*32+quad*8 ..+7]
    {
        const int kn = ((p + 1) & 31) * 32 + quad * 8;
#pragma unroll
        for (int f = 0; f < 4; ++f) {
            const float* __restrict__ src = xrow0 + (size_t)(f * 16 + l15) * HID + kn;
            xa[PH ^ 1][f][0] = *(const float4*)(src);
            xa[PH ^ 1][f][1] = *(const float4*)(src + 4);
        }
    }

    // 4. per f: convert current A-f32 to 3 bf16 pieces, then MFMA
#pragma unroll
    for (int f = 0; f < 4; ++f) {
        const float4 a0 = xa[PH][f][0], a1 = xa[PH][f][1];
        const float xs[8] = {a0.x, a0.y, a0.z, a0.w, a1.x, a1.y, a1.z, a1.w};
        ushort hv[8], mv[8], lv[8];
#pragma unroll
        for (int q = 0; q < 8; ++q) split3r(xs[q], hv[q], mv[q], lv[q]);
        bf16x8 axh, axm, axl;
#pragma unroll
        for (int q = 0; q < 8; ++q) { axh[q] = (short)hv[q]; axm[q] = (short)mv[q]; axl[q] = (short)lv[q]; }

        // logits: 6-product exact split
        accL[f] = __builtin_amdgcn_mfma_f32_16x16x32_bf16(axh, rwh[PH], accL[f], 0, 0, 0);
        accL[f] = __builtin_amdgcn_mfma_f32_16x16x32_bf16(axm, rwh[PH], accL[f], 0, 0, 0);
        accL[f] = __builtin_amdgcn_mfma_f32_16x16x32_bf16(axh, rwm[PH], accL[f], 0, 0, 0);
        accL[f] = __builtin_amdgcn_mfma_f32_16x16x32_bf16(axl, rwh[PH], accL[f], 0, 0, 0);
        accL[f] = __builtin_amdgcn_mfma_f32_16x16x32_bf16(axh, rwl[PH], accL[f], 0, 0, 0);
        accL[f] = __builtin_amdgcn_mfma_f32_16x16x32_bf16(axm, rwm[PH], accL[f], 0, 0, 0);
        // pred: 3 products (bit-exact order)
#pragma unroll
        for (int j = 0; j < 4; ++j) {
            accP[f][j] = __builtin_amdgcn_mfma_f32_16x16x32_bf16(axh, bwh[j], accP[f][j], 0, 0, 0);
            accP[f][j] = __builtin_amdgcn_mfma_f32_16x16x32_bf16(axm, bwh[j], accP[f][j], 0, 0, 0);
            accP[f][j] = __builtin_amdgcn_mfma_f32_16x16x32_bf16(axh, bwl[j], accP[f][j], 0, 0, 0);
        }
    }
    // no barrier — waves are independent until the epilogue
}

__global__ __launch_bounds__(256, 2) void fused_mfma(
    const float* __restrict__ X,
    const ushort* __restrict__ RWf, const ushort* __restrict__ W1f,
    const float* __restrict__ B1, const float* __restrict__ W2,
    const float* __restrict__ B2,
    float* __restrict__ logits, float* __restrict__ sel,
    float* __restrict__ wts, float* __restrict__ load_sum,
    float* __restrict__ ent_sum)
{
    __shared__ float red[4][64];
    __shared__ float Lt[64][65];

    const int tid  = threadIdx.x;
    const int lane = tid & 63;
    const int cg   = tid >> 6;           // wave 0..3 = col group
    const int quad = lane >> 4, l15 = lane & 15;
    const int tok0 = blockIdx.x * 64;

    f32x4 accL[4];
    f32x4 accP[4][4];
#pragma unroll
    for (int f = 0; f < 4; f++) {
        accL[f] = (f32x4){0.f, 0.f, 0.f, 0.f};
#pragma unroll
        for (int j = 0; j < 4; j++) accP[f][j] = (f32x4){0.f, 0.f, 0.f, 0.f};
    }

    const float* __restrict__ xrow0 = X + (size_t)tok0 * HID;

    bf16x8 rwh[2], rwm[2], rwl[2];
    float4 xa[2][4][2];

    // ---- prologue: A-f32(0) and RW(0) into buffer 0 ----
#pragma unroll
    for (int f = 0; f < 4; ++f) {
        const float* __restrict__ src = xrow0 + (size_t)(f * 16 + l15) * HID + quad * 8;
        xa[0][f][0] = *(const float4*)(src);
        xa[0][f][1] = *(const float4*)(src + 4);
    }
    {
        const ushort* __restrict__ rwp = RWf + (size_t)cg * 1536 + lane * 8;
        rwh[0] = *(const bf16x8*)(rwp);
        rwm[0] = *(const bf16x8*)(rwp + 512);
        rwl[0] = *(const bf16x8*)(rwp + 1024);
    }

    for (int p = 0; p < 32; p += 2) {
        kstep<0>(p,     cg, lane, quad, l15, xrow0, RWf, W1f,
                 rwh, rwm, rwl, xa, accL, accP);
        kstep<1>(p + 1, cg, lane, quad, l15, xrow0, RWf, W1f,
                 rwh, rwm, rwl, xa, accL, accP);
    }

    // ---- logits epilogue (C/D: row = quad*4 + r, col = l15; proven) ----
#pragma unroll
    for (int f = 0; f < 4; ++f)
#pragma unroll
        for (int r = 0; r < 4; ++r) {
            const int trow = f * 16 + quad * 4 + r;
            logits[(size_t)(tok0 + trow) * NEXP + cg * 16 + l15] = accL[f][r];
            Lt[trow][cg * 16 + l15] = accL[f][r];
        }

    // ---- pred epilogue: bias+ReLU+w2 dot, cross-wave reduce in LDS ----
    float w2r[4], b1r[4];
#pragma unroll
    for (int j = 0; j < 4; ++j) {
        const int col = (cg * 4 + j) * 16 + l15;
        w2r[j] = W2[col];
        b1r[j] = B1[col];
    }
#pragma unroll
    for (int f = 0; f < 4; ++f) {
#pragma unroll
        for (int r = 0; r < 4; ++r) {
            float s = 0.f;
#pragma unroll
            for (int j = 0; j < 4; ++j) {
                const float hval = accP[f][j][r] + b1r[j];
                s = fmaf(w2r[j], fmaxf(hval, 0.f), s);
            }
            s += __shfl_xor(s, 1);
            s += __shfl_xor(s, 2);
            s += __shfl_xor(s, 4);
            s += __shfl_xor(s, 8);
            if (l15 == 0)
                red[cg][f * 16 + quad * 4 + r] = s;
        }
    }
    __syncthreads();

    // ---- route (verbatim proven math), wave 0, token = lane ----
    if (cg == 0) {
        const int tok = tok0 + lane;

        float r[64];
#pragma unroll
        for (int e = 0; e < 64; e++) r[e] = Lt[lane][e];

        float v0 = -1e30f, v1 = -1e30f, v2 = -1e30f, v3 = -1e30f;
        int   i0 = 0, i1 = 0, i2 = 0, i3 = 0;
#pragma unroll
        for (int e = 0; e < 64; e++) {
            const float v = r[e];
            if (v > v3) {
                if (v > v2) {
                    if (v > v1) {
                        if (v > v0) { v3=v2;i3=i2; v2=v1;i2=i1; v1=v0;i1=i0; v0=v;i0=e; }
                        else        { v3=v2;i3=i2; v2=v1;i2=i1; v1=v;i1=e; }
                    } else          { v3=v2;i3=i2; v2=v;i2=e; }
                } else              { v3=v;i3=e; }
            }
        }

        const float s2 = red[0][lane] + red[1][lane] + red[2][lane]
                       + red[3][lane] + B2[0];
        const bool k4 = (s2 > 0.f);

        float w0, w1v, w2v, w3v;
        int   s1i, s2i, s3i;
        if (k4) {
            const float e0 = expf(v0 - v0), e1 = expf(v1 - v0);
            const float e2 = expf(v2 - v0), e3 = expf(v3 - v0);
            const float inv4 = 1.f / (e0 + e1 + e2 + e3);
            w0 = e0 * inv4; w1v = e1 * inv4; w2v = e2 * inv4; w3v = e3 * inv4;
            s1i = i1; s2i = i2; s3i = i3;
        } else {
            w0 = 1.f; w1v = 0.f; w2v = 0.f; w3v = 0.f;
            s1i = 0; s2i = 0; s3i = 0;
        }
        {
            float4 sv = {(float)i0, (float)s1i, (float)s2i, (float)s3i};
            float4 wv = {w0, w1v, w2v, w3v};
            *(float4*)(sel + (size_t)tok * 4) = sv;
            *(float4*)(wts + (size_t)tok * 4) = wv;
        }

        const float mx = v0;
        float S = 0.f, pz = 0.f;
#pragma unroll
        for (int e = 0; e < 64; e++) {
            const float z = r[e] - mx;
            const float t = expf(z);
            S += t; pz = fmaf(t, z, pz);
            r[e] = t;
        }
        const float inv = 1.f / S;
        float ent = logf(S) - pz * inv;

        float myload = 0.f;
#pragma unroll
        for (int e = 0; e < 64; e++) {
            float s = r[e] * inv;
            s += __shfl_xor(s, 1);
            s += __shfl_xor(s, 2);
            s += __shfl_xor(s, 4);
            s += __shfl_xor(s, 8);
            s += __shfl_xor(s, 16);
            s += __shfl_xor(s, 32);
            if (lane == e) myload = s;
        }
        atomicAdd(&load_sum[lane], myload);

        ent += __shfl_xor(ent, 1);
        ent += __shfl_xor(ent, 2);
        ent += __shfl_xor(ent, 4);
        ent += __shfl_xor(ent, 8);
        ent += __shfl_xor(ent, 16);
        ent += __shfl_xor(ent, 32);
        if (lane == 0) atomicAdd(ent_sum, ent);
    }
}

__global__ void finalize_kernel(const float* __restrict__ load_sum,
                                const float* __restrict__ ent_sum,
                                float* __restrict__ out_scal)
{
    const int lane = threadIdx.x;
    const float le = load_sum[lane] * (1.f / (float)NTOK);
    float s = le;
#pragma unroll
    for (int o = 32; o >= 1; o >>= 1) s += __shfl_xor(s, o);
    const float mean = s * (1.f / 64.f);
    const float d = le - mean;
    float v = d * d;
#pragma unroll
    for (int o = 32; o >= 1; o >>= 1) v += __shfl_xor(v, o);
    if (lane == 0) {
        out_scal[0] = v * (1.f / 63.f);
        out_scal[1] = ent_sum[0] * (1.f / (float)NTOK);
    }
}

extern "C" void kernel_launch(void* const* d_in, const int* in_sizes, int n_in,
                              void* d_out, int out_size, void* d_ws, size_t ws_size,
                              hipStream_t stream) {
    const float* X  = (const float*)d_in[0];
    const float* RW = (const float*)d_in[1];
    const float* W1 = (const float*)d_in[2];
    const float* B1 = (const float*)d_in[3];
    const float* W2 = (const float*)d_in[4];
    const float* B2 = (const float*)d_in[5];

    float* out    = (float*)d_out;
    float* logits = out;
    float* sel    = out + (size_t)NTOK * NEXP;
    float* wts    = sel + (size_t)NTOK * 4;
    float* scal   = wts + (size_t)NTOK * 4;

    float* s2ws     = (float*)d_ws;                       // [32768] (unused in v14)
    float* load_sum = s2ws + NTOK;                        // [64]
    float* ent_sum  = load_sum + 64;                      // [1]
    ushort* W1f = (ushort*)(s2ws + NTOK + 256);           // 1 MB, fragment-order
    ushort* RWf = W1f + (size_t)32 * 16384;               // 384 KB, fragment-order

    hipMemsetAsync(load_sum, 0, 65 * sizeof(float), stream);

    prep_kernel<<<320, 256, 0, stream>>>(W1, RW, W1f, RWf);
    fused_mfma<<<NTOK / 64, 256, 0, stream>>>(X, RWf, W1f, B1, W2, B2,
                                              logits, sel, wts, load_sum, ent_sum);
    finalize_kernel<<<1, 64, 0, stream>>>(load_sum, ent_sum, scal);
}